// Round 7
// baseline (660.805 us; speedup 1.0000x reference)
//
#include <hip/hip_runtime.h>
#include <hip/hip_bf16.h>

#define NROW 50000
#define NCOL 50000
#define DDIM 128

typedef __bf16 bf16_t;
typedef __bf16 bf16x2 __attribute__((ext_vector_type(2)));
typedef __bf16 bf16x8 __attribute__((ext_vector_type(8)));
typedef float  f32x4  __attribute__((ext_vector_type(4)));

__device__ __forceinline__ float lrelu(float v) { return v >= 0.f ? v : 0.01f * v; }

// adaptive scalar load: f ? f32 : bf16
__device__ __forceinline__ float ldf(const void* p, size_t i, bool f) {
    return f ? ((const float*)p)[i] : (float)((const bf16_t*)p)[i];
}

// ---------------- dtype detector (proven rounds 4-6 — unchanged) -----------
struct TensorTab { const void* p[18]; int n[18]; };

__global__ __launch_bounds__(256) void detect_dtypes(TensorTab T, int* flags)
{
    __shared__ int vb, vf;
    const int tid = threadIdx.x;
    for (int t = 0; t < 18; ++t) {
        if (tid == 0) { vb = 0; vf = 0; }
        __syncthreads();
        const int n = T.n[t];
        const bool isFloatArr = (t != 2 && t != 3 && t != 5 && t != 6) && n >= 2;
        if (isFloatArr) {
            int nw = n / 2;
            int wi = (int)(((long long)tid * nw) >> 8);
            unsigned w = ((const unsigned*)T.p[t])[wi];
            unsigned low = w & 0xffffu;
            if (low) {
                int e = (int)((low >> 7) & 0xffu);
                if (e >= 90 && e <= 141) atomicAdd(&vb, 1);
                else                     atomicAdd(&vf, 1);
            }
        }
        __syncthreads();
        if (tid == 0) flags[t] = (isFloatArr && vf > vb) ? 1 : 0; // 1 = f32
        __syncthreads();
    }
}

// ---------------- weight prep into MFMA B-frag order (one-time) ------------
struct WPtrs { const void* W[4]; int fi[4]; };

__global__ __launch_bounds__(256) void prep_weights(WPtrs P, const int* flags,
                                                    __bf16* outp)
{
    int slot = blockIdx.x * 256 + threadIdx.x;     // 4 * 2048
    if (slot >= 4 * 2048) return;
    int m = slot >> 11, sIdx = slot & 2047;
    bool f = flags[P.fi[m]] != 0;
    int l = sIdx & 63, combo = sIdx >> 6;
    int ct = combo >> 2, kk = combo & 3;
    int col  = ct * 16 + (l & 15);
    int krow = kk * 32 + (l >> 4) * 8;
    bf16x8 v;
#pragma unroll
    for (int j = 0; j < 8; ++j)
        v[j] = (__bf16)ldf(P.W[m], (size_t)(krow + j) * DDIM + col, f);
    ((bf16x8*)outp)[slot] = v;
}

// ---------------- exact CSR build ------------------------------------------
__global__ __launch_bounds__(256) void count_edges(
    const int* __restrict__ dst, int nE, int* __restrict__ counts)
{
    int e = blockIdx.x * 256 + threadIdx.x;
    if (e < nE) atomicAdd(&counts[dst[e]], 1);
}

// per-256-block exclusive scan; partials[b] = block total
__global__ __launch_bounds__(256) void scan_block(
    const int* __restrict__ in, int* __restrict__ offs,
    int* __restrict__ partials, int n)
{
    __shared__ int buf[256];
    int t = threadIdx.x, i = blockIdx.x * 256 + t;
    int v = (i < n) ? in[i] : 0;
    buf[t] = v;
    __syncthreads();
    for (int d = 1; d < 256; d <<= 1) {
        int x = (t >= d) ? buf[t - d] : 0;
        __syncthreads();
        buf[t] += x;
        __syncthreads();
    }
    if (i < n) offs[i] = buf[t] - v;          // exclusive within block
    if (t == 255) partials[blockIdx.x] = buf[255];
}

__global__ __launch_bounds__(256) void scan_partials(
    const int* __restrict__ partials, int* __restrict__ pprefix, int nb)
{
    __shared__ int buf[256];
    int t = threadIdx.x;
    int v = (t < nb) ? partials[t] : 0;
    buf[t] = v;
    __syncthreads();
    for (int d = 1; d < 256; d <<= 1) {
        int x = (t >= d) ? buf[t - d] : 0;
        __syncthreads();
        buf[t] += x;
        __syncthreads();
    }
    if (t < nb) pprefix[t] = buf[t] - v;      // exclusive over blocks
}

// fill CSR slots with {src, weight(f32 bits)}
__global__ __launch_bounds__(256) void fill_csr(
    const int* __restrict__ dst, const int* __restrict__ srcArr,
    const void* __restrict__ wArr, int nE,
    const int* __restrict__ offs, const int* __restrict__ pprefix,
    int* __restrict__ cursor, int2* __restrict__ slots2,
    const int* __restrict__ flags, int fiW)
{
    const bool fW = flags[fiW] != 0;
    int e = blockIdx.x * 256 + threadIdx.x;
    if (e >= nE) return;
    int d = dst[e];
    int pos = atomicAdd(&cursor[d], 1);
    int base = offs[d] + pprefix[d >> 8];
    int2 m;
    m.x = srcArr[e];
    m.y = __float_as_int(ldf(wArr, e, fW));
    slots2[base + pos] = m;
}

// ---------------- residual: out(f32) += feat (adaptive) --------------------
__global__ __launch_bounds__(256) void residual_add(
    float* __restrict__ out, const void* __restrict__ feat, int n4,
    const int* __restrict__ flags, int fiFeat)
{
    const bool fF = flags[fiFeat] != 0;
    int i = blockIdx.x * 256 + threadIdx.x;
    if (i >= n4) return;
    f32x4 o = ((const f32x4*)out)[i];
    f32x4 r;
#pragma unroll
    for (int j = 0; j < 4; ++j) r[j] = o[j] + ldf(feat, (size_t)i * 4 + j, fF);
    ((f32x4*)out)[i] = r;
}

// ---------------- fused segsum + MLP ---------------------------------------
// Block = 64 dest rows (4 waves x 16). Phase 1: per-wave CSR gather into LDS
// aggT (f32). Phase 2: A = eps*feat + aggT, MFMA MLP (weights prepped).
__device__ __forceinline__ void copy_wfrag(const __bf16* __restrict__ prep,
                                           __bf16* wf, int tid)
{
    const f32x4* sp = (const f32x4*)prep;
    f32x4* dp = (f32x4*)wf;
#pragma unroll
    for (int i = 0; i < 8; ++i) dp[tid + i * 256] = sp[tid + i * 256];
}

#define AGG_LD 132   // f32 row stride (+4 pad)

template <bool RESIDUAL>
__global__ __launch_bounds__(256) void mlp_fused(
    const void* __restrict__ gfeat,                   // gather source rows
    const void* __restrict__ feat,                    // MLP input / residual
    const int* __restrict__ counts, const int* __restrict__ offs,
    const int* __restrict__ pprefix, const int2* __restrict__ slots2,
    const void* __restrict__ b1, const void* __restrict__ b2,
    const void* __restrict__ epsp, float* __restrict__ out, int N,
    const int* __restrict__ flags,
    int fiG, int fiFeat, int fiB1, int fiB2, int fiEps,
    const __bf16* __restrict__ pW1, const __bf16* __restrict__ pW2)
{
    __shared__ alignas(16) char smem[64 * AGG_LD * 4 + 64 * 136 * 2]; // 51.2KB
    float*  aggT = (float*)smem;                     // [64][AGG_LD], phase 1
    __bf16* wf   = (__bf16*)smem;                    // 32KB alias, phase 2
    __bf16* h1t  = (__bf16*)(smem + 64 * AGG_LD * 4);// [64][136]

    const bool gF = (fiG == -1) ? true : (flags[fiG] != 0);
    const bool fF = flags[fiFeat] != 0;
    const bool fB1 = flags[fiB1] != 0, fB2 = flags[fiB2] != 0;
    const bool fE  = flags[fiEps] != 0;

    const int tid  = threadIdx.x;
    const int lane = tid & 63;
    const int wave = tid >> 6;
    const int quad = lane >> 4;
    const int r    = lane & 15;

    // ---- phase 1: segment sum for this block's 64 rows ----
    for (int rr = 0; rr < 16; ++rr) {
        int row = blockIdx.x * 64 + wave * 16 + rr;
        float sx = 0.f, sy = 0.f;
        if (row < N) {
            int base = offs[row] + pprefix[row >> 8];
            int cnt  = counts[row];
            for (int chunk = 0; chunk < cnt; chunk += 64) {
                int m = cnt - chunk; if (m > 64) m = 64;
                int2 meta = {0, 0};
                if (lane < m) meta = slots2[base + chunk + lane];
                for (int j = 0; j < m; ++j) {
                    int   sr = __shfl(meta.x, j);
                    float wv = __int_as_float(__shfl(meta.y, j));
                    float v0, v1;
                    if (gF) {
                        float2 v = ((const float2*)((const float*)gfeat +
                                    (size_t)sr * DDIM))[lane];
                        v0 = v.x; v1 = v.y;
                    } else {
                        bf16x2 v = ((const bf16x2*)((const bf16_t*)gfeat +
                                    (size_t)sr * DDIM))[lane];
                        v0 = (float)v[0]; v1 = (float)v[1];
                    }
                    sx += v0 * wv; sy += v1 * wv;
                }
            }
        }
        ((float2*)(aggT + (wave * 16 + rr) * AGG_LD))[lane] =
            make_float2(sx, sy);
    }
    __syncthreads();   // aggT complete

    // ---- phase 2a: A-fragments  x = eps1*feat + agg ----
    const float eps1 = 1.f + ldf(epsp, 0, fE);
    const int rowBase = blockIdx.x * 64 + wave * 16;

    bf16x8 a[4];
    {
        int rowA = rowBase + r;
        const float* ga = aggT + (size_t)(wave * 16 + r) * AGG_LD + quad * 8;
        if (rowA < N) {
            size_t fb = (size_t)rowA * DDIM + quad * 8;
            if (fF) {
                const f32x4* fp = (const f32x4*)((const float*)feat + fb);
#pragma unroll
                for (int kk = 0; kk < 4; ++kk) {
                    f32x4 f0 = fp[kk * 8], f1 = fp[kk * 8 + 1];
                    f32x4 g0 = *(const f32x4*)(ga + kk * 32);
                    f32x4 g1 = *(const f32x4*)(ga + kk * 32 + 4);
                    bf16x8 av;
#pragma unroll
                    for (int j = 0; j < 4; ++j) {
                        av[j]     = (__bf16)(f0[j] * eps1 + g0[j]);
                        av[j + 4] = (__bf16)(f1[j] * eps1 + g1[j]);
                    }
                    a[kk] = av;
                }
            } else {
                const bf16x8* fp = (const bf16x8*)((const bf16_t*)feat + fb);
#pragma unroll
                for (int kk = 0; kk < 4; ++kk) {
                    bf16x8 fv = fp[kk * 4];
                    f32x4 g0 = *(const f32x4*)(ga + kk * 32);
                    f32x4 g1 = *(const f32x4*)(ga + kk * 32 + 4);
                    bf16x8 av;
#pragma unroll
                    for (int j = 0; j < 4; ++j) {
                        av[j]     = (__bf16)((float)fv[j]     * eps1 + g0[j]);
                        av[j + 4] = (__bf16)((float)fv[j + 4] * eps1 + g1[j]);
                    }
                    a[kk] = av;
                }
            }
        } else {
#pragma unroll
            for (int kk = 0; kk < 4; ++kk)
#pragma unroll
                for (int j = 0; j < 8; ++j) a[kk][j] = (__bf16)0.f;
        }
    }
    __syncthreads();   // all aggT reads done; wf may overwrite

    copy_wfrag(pW1, wf, tid);
    __syncthreads();   // W1 frags ready

    const bf16x8* wv = (const bf16x8*)wf;
#pragma unroll
    for (int ct = 0; ct < 8; ++ct) {
        f32x4 acc = {0.f, 0.f, 0.f, 0.f};
#pragma unroll
        for (int kk = 0; kk < 4; ++kk)
            acc = __builtin_amdgcn_mfma_f32_16x16x32_bf16(
                a[kk], wv[(ct * 4 + kk) * 64 + lane], acc, 0, 0, 0);
        float bias = ldf(b1, ct * 16 + r, fB1);
#pragma unroll
        for (int gg = 0; gg < 4; ++gg)   // D: m = quad*4+gg, n = ct*16+r
            h1t[(wave * 16 + quad * 4 + gg) * 136 + ct * 16 + r] =
                (__bf16)lrelu(acc[gg] + bias);
    }
    __syncthreads();   // h1 complete; wf free

    bf16x8 a2[4];
#pragma unroll
    for (int kk = 0; kk < 4; ++kk)
        a2[kk] = *(const bf16x8*)&h1t[(wave * 16 + r) * 136 + kk * 32 + quad * 8];

    copy_wfrag(pW2, wf, tid);
    __syncthreads();   // W2 frags ready

#pragma unroll
    for (int ct = 0; ct < 8; ++ct) {
        f32x4 acc = {0.f, 0.f, 0.f, 0.f};
#pragma unroll
        for (int kk = 0; kk < 4; ++kk)
            acc = __builtin_amdgcn_mfma_f32_16x16x32_bf16(
                a2[kk], wv[(ct * 4 + kk) * 64 + lane], acc, 0, 0, 0);
        float bias = ldf(b2, ct * 16 + r, fB2);
#pragma unroll
        for (int gg = 0; gg < 4; ++gg) {
            int row = rowBase + quad * 4 + gg;
            if (row < N) {
                int col = ct * 16 + r;
                float v = lrelu(acc[gg] + bias);
                if (RESIDUAL) v += ldf(feat, (size_t)row * DDIM + col, fF);
                out[(size_t)row * DDIM + col] = v;
            }
        }
    }
}

extern "C" void kernel_launch(void* const* d_in, const int* in_sizes, int n_in,
                              void* d_out, int out_size, void* d_ws, size_t ws_size,
                              hipStream_t stream)
{
    const int* src_c2r = (const int*)d_in[2];
    const int* dst_c2r = (const int*)d_in[3];
    const int* src_r2c = (const int*)d_in[5];
    const int* dst_r2c = (const int*)d_in[6];
    const int nE = in_sizes[2];

    // ws layout (≈5.5 MB; round-6 evidence: ws ≥ 6.73 MB available)
    char* w = (char*)d_ws;
    int*    flags    = (int*)w;                       // 128 B
    __bf16* wfprep   = (__bf16*)(w + 128);            // 128 KB
    int*    counts   = (int*)(w + 131200);            // 200 KB
    int*    offs     = (int*)(w + 331200);            // 200 KB
    int*    cursor   = (int*)(w + 531200);            // 200 KB
    int*    partials = (int*)(w + 731200);            // 1 KB
    int*    pprefix  = (int*)(w + 732224);            // 1 KB
    int2*   slots2   = (int2*)(w + 733248);           // nE*8 = 4.8 MB

    TensorTab T;
    for (int i = 0; i < 18; ++i) { T.p[i] = d_in[i]; T.n[i] = in_sizes[i]; }

    float* out_row = (float*)d_out;
    float* out_col = out_row + (size_t)NROW * DDIM;

    const int eblocks = (nE + 255) / 256;
    const int nblocks = (NROW + 255) / 256;           // 196 (NROW==NCOL)
    const int mblocks = (NROW + 63) / 64;             // 782

    detect_dtypes<<<1, 256, 0, stream>>>(T, flags);

    WPtrs P;
    P.W[0] = d_in[8];  P.fi[0] = 8;    // W1_c2r
    P.W[1] = d_in[10]; P.fi[1] = 10;   // W2_c2r
    P.W[2] = d_in[12]; P.fi[2] = 12;   // W1_r2c
    P.W[3] = d_in[14]; P.fi[3] = 14;   // W2_r2c
    prep_weights<<<32, 256, 0, stream>>>(P, flags, wfprep);

    // ---- stage 1: col -> row ----
    hipMemsetAsync(counts, 0, 600000, stream);        // counts+offs+cursor
    count_edges<<<eblocks, 256, 0, stream>>>(dst_c2r, nE, counts);
    scan_block<<<nblocks, 256, 0, stream>>>(counts, offs, partials, NROW);
    scan_partials<<<1, 256, 0, stream>>>(partials, pprefix, nblocks);
    fill_csr<<<eblocks, 256, 0, stream>>>(dst_c2r, src_c2r, d_in[4], nE,
        offs, pprefix, cursor, slots2, flags, 4);
    // out_row <- h_row (f32, no residual yet; scatter-2 source)
    mlp_fused<false><<<mblocks, 256, 0, stream>>>(
        d_in[1], d_in[0], counts, offs, pprefix, slots2,
        d_in[9], d_in[11], d_in[16], out_row, NROW, flags,
        1, 0, 9, 11, 16, wfprep + 0 * 16384, wfprep + 1 * 16384);

    // ---- stage 2: row -> col ----
    hipMemsetAsync(counts, 0, 600000, stream);
    count_edges<<<eblocks, 256, 0, stream>>>(dst_r2c, nE, counts);
    scan_block<<<nblocks, 256, 0, stream>>>(counts, offs, partials, NCOL);
    scan_partials<<<1, 256, 0, stream>>>(partials, pprefix, nblocks);
    fill_csr<<<eblocks, 256, 0, stream>>>(dst_r2c, src_r2c, d_in[7], nE,
        offs, pprefix, cursor, slots2, flags, 7);
    // gathers h from out_row (f32), writes out_col with residual
    mlp_fused<true><<<mblocks, 256, 0, stream>>>(
        out_row, d_in[1], counts, offs, pprefix, slots2,
        d_in[13], d_in[15], d_in[17], out_col, NCOL, flags,
        -1, 1, 13, 15, 17, wfprep + 2 * 16384, wfprep + 3 * 16384);
    // now safe to add the row residual in place
    residual_add<<<(NROW * DDIM / 4 + 255) / 256, 256, 0, stream>>>(
        out_row, d_in[0], NROW * DDIM / 4, flags, 0);
}